// Round 4
// baseline (461.143 us; speedup 1.0000x reference)
//
#include <hip/hip_runtime.h>
#include <hip/hip_bf16.h>
#include <math.h>

typedef __bf16 bf16_t;
typedef __bf16 bf16x8 __attribute__((ext_vector_type(8)));
typedef __bf16 bf16x4 __attribute__((ext_vector_type(4)));
typedef float  f32x4  __attribute__((ext_vector_type(4)));
typedef float  f32x16 __attribute__((ext_vector_type(16)));

#define D 768

// ---------------- block reduction helpers (blockDim == 256) ----------------
__device__ inline double blk_sum(double x, double* s) {
#pragma unroll
  for (int m = 32; m; m >>= 1) x += __shfl_xor(x, m);
  __syncthreads();
  if ((threadIdx.x & 63) == 0) s[threadIdx.x >> 6] = x;
  __syncthreads();
  return s[0] + s[1] + s[2] + s[3];
}

__device__ inline double blk_max(double x, double* s) {
#pragma unroll
  for (int m = 32; m; m >>= 1) x = fmax(x, __shfl_xor(x, m));
  __syncthreads();
  if ((threadIdx.x & 63) == 0) s[threadIdx.x >> 6] = x;
  __syncthreads();
  return fmax(fmax(s[0], s[1]), fmax(s[2], s[3]));
}

// ---------------- K1: L2-normalize rows (f64-accumulated norm) -------------
__global__ __launch_bounds__(256) void norm_rows(const float* __restrict__ src,
                                                 float* __restrict__ dst_f32,
                                                 bf16_t* __restrict__ dst_bf,
                                                 int n_valid, int n_total) {
  int row  = blockIdx.x * 4 + (threadIdx.x >> 6);
  int lane = threadIdx.x & 63;
  if (row >= n_total) return;
  if (row >= n_valid) {
    if (dst_bf) {
      bf16_t* drow = dst_bf + (size_t)row * D;
      bf16x4 z = {(bf16_t)0.f, (bf16_t)0.f, (bf16_t)0.f, (bf16_t)0.f};
#pragma unroll
      for (int j = 0; j < 3; j++) *(bf16x4*)(drow + 4 * (lane + 64 * j)) = z;
    }
    return;
  }
  const float4* s = (const float4*)(src + (size_t)row * D);
  float4 v[3];
  double ss = 0.0;
#pragma unroll
  for (int j = 0; j < 3; j++) {
    v[j] = s[lane + 64 * j];
    ss += (double)v[j].x * v[j].x + (double)v[j].y * v[j].y +
          (double)v[j].z * v[j].z + (double)v[j].w * v[j].w;
  }
#pragma unroll
  for (int m = 32; m; m >>= 1) ss += __shfl_xor(ss, m);
  double inv = 1.0 / fmax(sqrt(ss), 1e-12);
  float4 o[3];
#pragma unroll
  for (int j = 0; j < 3; j++) {
    o[j].x = (float)((double)v[j].x * inv);
    o[j].y = (float)((double)v[j].y * inv);
    o[j].z = (float)((double)v[j].z * inv);
    o[j].w = (float)((double)v[j].w * inv);
  }
  if (dst_f32) {
    float* drow = dst_f32 + (size_t)row * D;
#pragma unroll
    for (int j = 0; j < 3; j++) ((float4*)drow)[lane + 64 * j] = o[j];
  }
  if (dst_bf) {
    bf16_t* drow = dst_bf + (size_t)row * D;
#pragma unroll
    for (int j = 0; j < 3; j++) {
      bf16x4 ob;
      ob[0] = (bf16_t)o[j].x; ob[1] = (bf16_t)o[j].y;
      ob[2] = (bf16_t)o[j].z; ob[3] = (bf16_t)o[j].w;
      *(bf16x4*)(drow + 4 * (lane + 64 * j)) = ob;
    }
  }
}

// ---------------- K2: max-sim GEMM v3 (canonical LDS-LDS, 32x32x16) --------
// Block tile 256(M=W rows) x 128(N=protos); 4 waves, each 128x64 via 4x2
// frags of mfma_f32_32x32x16_bf16. K-step 32, double-buffered, XOR-swizzled
// LDS. W read raw f32 once (thread stages its own row -> f32 norm fused,
// scale-invariant bf16 quantization); epilogue divides row-max by norm.
// Grid: x = N-tiles (8, innermost -> L2/L3 A-slab sharing), y = M-tiles.

// LDS index (bf16 units) for row r, 16B chunk c (c = 0..3 over 32 k-elems)
__device__ inline int lidx(int r, int c) {
  return r * 32 + ((c * 8) ^ ((r & 7) << 3));
}

__global__ __launch_bounds__(256, 2) void maxsim_gemm(
    const float* __restrict__ W, const bf16_t* __restrict__ Tb,
    float* __restrict__ maxsim, int V, int U) {
  __shared__ __align__(16) bf16_t aT[2][256 * 32];
  __shared__ __align__(16) bf16_t bT[2][128 * 32];
  __shared__ float norm2s[256];

  const int tid  = threadIdx.x;
  const int lane = tid & 63;
  const int wid  = tid >> 6;
  const int wm   = wid >> 1;      // 0..1 (M half)
  const int wn   = wid & 1;       // 0..1 (N half)
  const int l31  = lane & 31;
  const int lh   = lane >> 5;     // k-half selector

  const int rgA = blockIdx.y * 256 + tid;     // this thread's A row (global)
  const bool va = rgA < V;
  const float* Wp = W + (size_t)rgA * D;
  // B: thread stages proto p = tid>>1, k-half kh = tid&1 (16 bf16)
  const int pg = blockIdx.x * 128 + (tid >> 1);
  const bf16_t* Tp = Tb + (size_t)pg * D + (tid & 1) * 16;

  float ss = 0.f;  // this thread's row sum of squares (accumulated over K)

  auto stageA = [&](int buf, int k0) {
    bf16_t* dst = &aT[buf][0];
    if (va) {
      const float4* s = (const float4*)(Wp + k0);
      float4 x[8];
#pragma unroll
      for (int i = 0; i < 8; i++) x[i] = s[i];
      float ls = 0.f;
#pragma unroll
      for (int i = 0; i < 8; i++)
        ls += x[i].x * x[i].x + x[i].y * x[i].y + x[i].z * x[i].z + x[i].w * x[i].w;
      ss += ls;
#pragma unroll
      for (int c = 0; c < 4; c++) {
        bf16x8 f;
        f[0] = (bf16_t)x[2 * c].x;     f[1] = (bf16_t)x[2 * c].y;
        f[2] = (bf16_t)x[2 * c].z;     f[3] = (bf16_t)x[2 * c].w;
        f[4] = (bf16_t)x[2 * c + 1].x; f[5] = (bf16_t)x[2 * c + 1].y;
        f[6] = (bf16_t)x[2 * c + 1].z; f[7] = (bf16_t)x[2 * c + 1].w;
        *(bf16x8*)&dst[lidx(tid, c)] = f;
      }
    } else {
      bf16x8 z;
#pragma unroll
      for (int e = 0; e < 8; e++) z[e] = (bf16_t)0.f;
#pragma unroll
      for (int c = 0; c < 4; c++) *(bf16x8*)&dst[lidx(tid, c)] = z;
    }
  };

  auto stageB = [&](int buf, int k0) {
    bf16_t* dst = &bT[buf][0];
    const bf16x8* s = (const bf16x8*)(Tp + k0);
    bf16x8 b0 = s[0], b1 = s[1];
    const int p = tid >> 1, kh = tid & 1;
    *(bf16x8*)&dst[lidx(p, kh * 2)]     = b0;
    *(bf16x8*)&dst[lidx(p, kh * 2 + 1)] = b1;
  };

  f32x16 acc[4][2];
#pragma unroll
  for (int m = 0; m < 4; m++)
#pragma unroll
    for (int n = 0; n < 2; n++)
#pragma unroll
      for (int r = 0; r < 16; r++) acc[m][n][r] = 0.f;

  stageA(0, 0);
  stageB(0, 0);
  const int NK = D / 32;  // 24
  for (int ks = 0; ks < NK; ks++) {
    __syncthreads();
    if (ks + 1 < NK) {
      stageA((ks + 1) & 1, (ks + 1) * 32);
      stageB((ks + 1) & 1, (ks + 1) * 32);
    }
    const bf16_t* ab = &aT[ks & 1][0];
    const bf16_t* bb = &bT[ks & 1][0];
    bf16x8 af[2][4], bfr[2][2];
#pragma unroll
    for (int h = 0; h < 2; h++) {
#pragma unroll
      for (int m = 0; m < 4; m++)
        af[h][m] = *(const bf16x8*)&ab[lidx(wm * 128 + m * 32 + l31, h * 2 + lh)];
#pragma unroll
      for (int n = 0; n < 2; n++)
        bfr[h][n] = *(const bf16x8*)&bb[lidx(wn * 64 + n * 32 + l31, h * 2 + lh)];
    }
#pragma unroll
    for (int h = 0; h < 2; h++)
#pragma unroll
      for (int m = 0; m < 4; m++)
#pragma unroll
        for (int n = 0; n < 2; n++)
          acc[m][n] = __builtin_amdgcn_mfma_f32_32x32x16_bf16(
              af[h][m], bfr[h][n], acc[m][n], 0, 0, 0);
  }

  __syncthreads();
  norm2s[tid] = ss;
  __syncthreads();

  // Epilogue: per m-frag, max over proto cols (masked to U), /norm, store.
#pragma unroll
  for (int m = 0; m < 4; m++) {
    float mx[16];
#pragma unroll
    for (int r = 0; r < 16; r++) {
      float v = -1e30f;
#pragma unroll
      for (int n = 0; n < 2; n++) {
        int gcol = blockIdx.x * 128 + wn * 64 + n * 32 + l31;
        if (gcol < U) v = fmaxf(v, acc[m][n][r]);
      }
      mx[r] = v;
    }
#pragma unroll
    for (int sh = 1; sh < 32; sh <<= 1)
#pragma unroll
      for (int r = 0; r < 16; r++) mx[r] = fmaxf(mx[r], __shfl_xor(mx[r], sh));
    if (l31 == 0) {
#pragma unroll
      for (int r = 0; r < 16; r++) {
        int rloc = wm * 128 + m * 32 + (r & 3) + 8 * (r >> 2) + 4 * lh;
        float inv = 1.0f / fmaxf(sqrtf(norm2s[rloc]), 1e-12f);
        maxsim[blockIdx.y * 256 + rloc] = mx[r] * inv;
      }
    }
  }
}

// ---------------- K3: approx sim GEMM (bf16 MFMA) ---------------------------
#define LDSROW 776  // 768 + 8 pad (bf16 units)

__global__ __launch_bounds__(256) void simf_gemm(const float* __restrict__ SUPn,
                                                 const bf16_t* __restrict__ TSb,
                                                 float* __restrict__ sim,
                                                 int Q, int ld, int NTB) {
  __shared__ __align__(16) bf16_t lds[2][16 * LDSROW];
  const int tid  = threadIdx.x;
  const int lane = tid & 63;
  const int rowbase = blockIdx.x * 64 + (tid >> 6) * 16;
  const int arow_i  = rowbase + (lane & 15);

  bf16x8 a[24];
  if (arow_i < Q) {
    const float* ar = SUPn + (size_t)arow_i * D + ((lane >> 4) * 8);
#pragma unroll
    for (int kk = 0; kk < 24; kk++) {
      float4 x = *(const float4*)(ar + kk * 32);
      float4 y = *(const float4*)(ar + kk * 32 + 4);
      bf16x8 f;
      f[0] = (bf16_t)x.x; f[1] = (bf16_t)x.y; f[2] = (bf16_t)x.z; f[3] = (bf16_t)x.w;
      f[4] = (bf16_t)y.x; f[5] = (bf16_t)y.y; f[6] = (bf16_t)y.z; f[7] = (bf16_t)y.w;
      a[kk] = f;
    }
  } else {
#pragma unroll
    for (int kk = 0; kk < 24; kk++) {
      bf16x8 f;
#pragma unroll
      for (int e = 0; e < 8; e++) f[e] = (bf16_t)0.f;
      a[kk] = f;
    }
  }

  auto stage = [&](int buf, int nt) {
    const ulonglong2* src = (const ulonglong2*)(TSb + (size_t)nt * 16 * D);
#pragma unroll
    for (int j = 0; j < 6; j++) {
      int c = tid + j * 256;
      int rr = c / 96, w = c % 96;
      *(ulonglong2*)&lds[buf][rr * LDSROW + w * 8] = src[c];
    }
  };

  stage(0, 0);
  for (int nt = 0; nt < NTB; nt++) {
    __syncthreads();
    if (nt + 1 < NTB) stage((nt + 1) & 1, nt + 1);
    f32x4 acc = {0.f, 0.f, 0.f, 0.f};
    const bf16_t* brow = &lds[nt & 1][(lane & 15) * LDSROW + ((lane >> 4) * 8)];
#pragma unroll
    for (int kk = 0; kk < 24; kk++) {
      bf16x8 b = *(const bf16x8*)(brow + kk * 32);
      acc = __builtin_amdgcn_mfma_f32_16x16x32_bf16(a[kk], b, acc, 0, 0, 0);
    }
    const int bcol = nt * 16 + (lane & 15);
    const int q0   = rowbase + ((lane >> 4) << 2);
    float* dst = sim + (size_t)bcol * ld + q0;
    if (q0 + 3 < Q) {
      *(f32x4*)dst = acc;
    } else {
#pragma unroll
      for (int j = 0; j < 4; j++)
        if (q0 + j < Q) dst[j] = acc[j];
    }
  }
}

// ---------------- K4: per-row top-16 on f32 sims (packed u64 keys) ----------
__device__ inline unsigned long long pack_key(float v, int q) {
  unsigned u = __float_as_uint(v);
  u = (u & 0x80000000u) ? ~u : (u | 0x80000000u);  // order-preserving map
  return ((unsigned long long)u << 32) | (unsigned)(0xFFFFFFFFu - (unsigned)q);
}

__global__ __launch_bounds__(256) void topk16_f32(const float* __restrict__ sim,
                                                  int* __restrict__ cand,
                                                  int Q, int ld) {
  __shared__ unsigned long long sk[256][16];
  const int b = blockIdx.x, tid = threadIdx.x;
  const float* row = sim + (size_t)b * ld;
  unsigned long long best[16];
#pragma unroll
  for (int k = 0; k < 16; k++) best[k] = 0ull;
  for (int q = tid; q < Q; q += 256) {
    unsigned long long key = pack_key(row[q], q);
    if (key > best[15]) {
      best[15] = key;
      for (int k = 15; k > 0; k--) {
        if (best[k] > best[k - 1]) {
          unsigned long long t = best[k]; best[k] = best[k - 1]; best[k - 1] = t;
        } else break;
      }
    }
  }
#pragma unroll
  for (int k = 0; k < 16; k++) sk[tid][k] = best[k];
  for (int stride = 128; stride >= 1; stride >>= 1) {
    __syncthreads();
    if (tid < stride) {
      unsigned long long out[16];
      int pa = 0, pb = 0;
#pragma unroll
      for (int k = 0; k < 16; k++) {
        unsigned long long va = sk[tid][pa], vb = sk[tid + stride][pb];
        if (va >= vb) { out[k] = va; pa++; }
        else          { out[k] = vb; pb++; }
      }
#pragma unroll
      for (int k = 0; k < 16; k++) sk[tid][k] = out[k];
    }
  }
  __syncthreads();
  if (tid < 16)
    cand[b * 16 + tid] = (int)(0xFFFFFFFFu - (unsigned)(sk[0][tid] & 0xFFFFFFFFull));
}

// ---------------- K5: exact f64 rescore of 16 candidates -> top-8 ----------
__global__ __launch_bounds__(256) void rescore(const float* __restrict__ SUPn,
                                               const float* __restrict__ TSn,
                                               const int* __restrict__ cand,
                                               int* __restrict__ topk) {
  __shared__ float tsrow[D];
  __shared__ double sval[16];
  __shared__ int    sidx[16];
  const int b = blockIdx.x, tid = threadIdx.x;
  const int lane = tid & 63, w = tid >> 6;
#pragma unroll
  for (int j = 0; j < 3; j++) tsrow[tid + 256 * j] = TSn[(size_t)b * D + tid + 256 * j];
  __syncthreads();
  for (int c = w; c < 16; c += 4) {
    int q = cand[b * 16 + c];
    const float* sr = SUPn + (size_t)q * D;
    double dot = 0.0;
#pragma unroll
    for (int i = 0; i < 12; i++)
      dot += (double)sr[lane + 64 * i] * (double)tsrow[lane + 64 * i];
#pragma unroll
    for (int m = 32; m; m >>= 1) dot += __shfl_xor(dot, m);
    if (lane == 0) { sval[c] = dot; sidx[c] = q; }
  }
  __syncthreads();
  if (tid == 0) {
    for (int i = 1; i < 16; i++) {
      double v = sval[i]; int ix = sidx[i];
      int j = i - 1;
      while (j >= 0 && (sval[j] < v || (sval[j] == v && sidx[j] > ix))) {
        sval[j + 1] = sval[j]; sidx[j + 1] = sidx[j]; j--;
      }
      sval[j + 1] = v; sidx[j + 1] = ix;
    }
#pragma unroll
    for (int k = 0; k < 8; k++) topk[b * 8 + k] = sidx[k];
  }
}

// ---------------- K6: gather rows to output + positive + pos_sim -----------
__global__ __launch_bounds__(256) void gather_pos(const float* __restrict__ SUPn,
                                                  const float* __restrict__ TSn,
                                                  const int* __restrict__ topk,
                                                  float* __restrict__ out,
                                                  double* __restrict__ pos_sim, int Q) {
  __shared__ int idx[8];
  __shared__ double red[4];
  const int b = blockIdx.x, tid = threadIdx.x;
  if (tid < 8) idx[tid] = topk[b * 8 + tid];
  __syncthreads();
  float mean[3] = {0.f, 0.f, 0.f};
#pragma unroll
  for (int k = 0; k < 8; k++) {
    const float* sr = SUPn + (size_t)idx[k] * D;
    float* orow = out + ((size_t)b * 8 + k) * D;
#pragma unroll
    for (int j = 0; j < 3; j++) {
      float x = sr[tid + 256 * j];
      orow[tid + 256 * j] = x;
      mean[j] += x;
    }
  }
#pragma unroll
  for (int j = 0; j < 3; j++) mean[j] *= 0.125f;
  double ss = 0.0;
#pragma unroll
  for (int j = 0; j < 3; j++) ss += (double)mean[j] * mean[j];
  ss = blk_sum(ss, red);
  double inv = 1.0 / fmax(sqrt(ss), 1e-12);
  double dot = 0.0;
#pragma unroll
  for (int j = 0; j < 3; j++)
    dot += (double)TSn[(size_t)b * D + tid + 256 * j] * ((double)mean[j] * inv);
  dot = blk_sum(dot, red);
  if (tid == 0) pos_sim[b] = dot / (double)0.07f;
}

// ---------------- K7: per-row NNCL logsumexp --------------------------------
__global__ __launch_bounds__(256) void nncl_rows(const float* __restrict__ TSn,
                                                 const double* __restrict__ pos_sim,
                                                 double* __restrict__ row_loss) {
  __shared__ float tsb[D];
  __shared__ double red[4];
  const int b = blockIdx.x, c = threadIdx.x;
#pragma unroll
  for (int j = 0; j < 3; j++) tsb[c + 256 * j] = TSn[(size_t)b * D + c + 256 * j];
  __syncthreads();
  const float* tc = TSn + (size_t)c * D;
  double dot = 0.0;
  for (int e = 0; e < D; e += 4) {
    float4 t4 = *(const float4*)(tc + e);
    dot += (double)tsb[e] * t4.x + (double)tsb[e + 1] * t4.y +
           (double)tsb[e + 2] * t4.z + (double)tsb[e + 3] * t4.w;
  }
  const bool diag = (c == b);
  double logit = dot / (double)0.07f;
  double p = pos_sim[b];
  double m = blk_max(diag ? -1e300 : logit, red);
  m = fmax(m, p);
  double term = diag ? 0.0 : exp(logit - m);
  double ssum = blk_sum(term, red);
  ssum += exp(p - m);
  if (c == 0) row_loss[b] = (log(ssum) + m) - p;
}

// ---------------- K8: finalize scalars --------------------------------------
__global__ __launch_bounds__(256) void finalize(const float* __restrict__ maxsim,
                                                const double* __restrict__ row_loss,
                                                float* __restrict__ d_out, int out_size,
                                                int V, int B) {
  __shared__ double red[4];
  const int tid = threadIdx.x;
  double s1 = 0.0;
  for (int v = tid; v < V; v += 256) s1 += 2.0 - 2.0 * (double)maxsim[v];
  s1 = blk_sum(s1, red);
  __syncthreads();
  double s2 = 0.0;
  for (int b = tid; b < B; b += 256) s2 += row_loss[b];
  s2 = blk_sum(s2, red);
  if (tid == 0) {
    d_out[out_size - 2] = (float)(s1 / ((double)V * (double)D));
    d_out[out_size - 1] = (float)(s2 / (double)B);
  }
}

// ---------------- host launcher ---------------------------------------------
extern "C" void kernel_launch(void* const* d_in, const int* in_sizes, int n_in,
                              void* d_out, int out_size, void* d_ws, size_t ws_size,
                              hipStream_t stream) {
  const float* TS  = (const float*)d_in[0];
  const float* W   = (const float*)d_in[1];
  const float* T   = (const float*)d_in[2];
  const float* SUP = (const float*)d_in[3];
  const int B = in_sizes[0] / D;   // 256
  const int V = in_sizes[1] / D;   // 50257
  const int U = in_sizes[2] / D;   // 1000
  const int Q = in_sizes[3] / D;   // 10000
  const int UPAD = 1024;           // N padded to 8 x 128 tiles
  const int VPAD = (V + 255) & ~255; // 50432 (197 x 256)
  const int QPAD = (Q + 63) & ~63; // 10048
  const int NTB  = B / 16;         // 16

  char* ws = (char*)d_ws;
  size_t off = 0;
  auto alloc = [&](size_t bytes) -> char* {
    char* p = ws + off;
    off = (off + bytes + 255) & ~(size_t)255;
    return p;
  };
  bf16_t* t_bf   = (bf16_t*)alloc((size_t)UPAD * D * 2);
  float*  maxsim = (float*) alloc((size_t)VPAD * 4);
  float*  ts_n   = (float*) alloc((size_t)B * D * 4);
  bf16_t* ts_bf  = (bf16_t*)alloc((size_t)B * D * 2);
  float*  sup_n  = (float*) alloc((size_t)Q * D * 4);
  float*  simf   = (float*) alloc((size_t)B * QPAD * 4);
  int*    cand   = (int*)   alloc((size_t)B * 16 * 4);
  int*    tki    = (int*)   alloc((size_t)B * 8 * 4);
  double* psim   = (double*)alloc((size_t)B * 8);
  double* rloss  = (double*)alloc((size_t)B * 8);
  (void)ws_size; (void)n_in;

  norm_rows<<<UPAD / 4, 256, 0, stream>>>(T,   nullptr, t_bf,  U, UPAD);
  norm_rows<<<B    / 4, 256, 0, stream>>>(TS,  ts_n,  ts_bf,   B, B);
  norm_rows<<<(Q + 3) / 4, 256, 0, stream>>>(SUP, sup_n, nullptr, Q, Q);

  dim3 gms(UPAD / 128, VPAD / 256);  // x = N-tiles innermost (A-slab sharing)
  maxsim_gemm<<<gms, 256, 0, stream>>>(W, t_bf, maxsim, V, U);

  simf_gemm<<<QPAD / 64, 256, 0, stream>>>(sup_n, ts_bf, simf, Q, QPAD, NTB);
  topk16_f32<<<B, 256, 0, stream>>>(simf, cand, Q, QPAD);
  rescore<<<B, 256, 0, stream>>>(sup_n, ts_n, cand, tki);

  gather_pos<<<B, 256, 0, stream>>>(sup_n, ts_n, tki, (float*)d_out, psim, Q);
  nncl_rows<<<B, 256, 0, stream>>>(ts_n, psim, rloss);
  finalize<<<1, 256, 0, stream>>>(maxsim, rloss, (float*)d_out, out_size, V, B);
}

// Round 5
// 342.772 us; speedup vs baseline: 1.3453x; 1.3453x over previous
//
#include <hip/hip_runtime.h>
#include <hip/hip_bf16.h>
#include <math.h>

typedef __bf16 bf16_t;
typedef __bf16 bf16x8 __attribute__((ext_vector_type(8)));
typedef __bf16 bf16x4 __attribute__((ext_vector_type(4)));
typedef float  f32x4  __attribute__((ext_vector_type(4)));

#define D 768

// ---------------- block reduction helpers (blockDim == 256) ----------------
__device__ inline double blk_sum(double x, double* s) {
#pragma unroll
  for (int m = 32; m; m >>= 1) x += __shfl_xor(x, m);
  __syncthreads();
  if ((threadIdx.x & 63) == 0) s[threadIdx.x >> 6] = x;
  __syncthreads();
  return s[0] + s[1] + s[2] + s[3];
}

__device__ inline double blk_max(double x, double* s) {
#pragma unroll
  for (int m = 32; m; m >>= 1) x = fmax(x, __shfl_xor(x, m));
  __syncthreads();
  if ((threadIdx.x & 63) == 0) s[threadIdx.x >> 6] = x;
  __syncthreads();
  return fmax(fmax(s[0], s[1]), fmax(s[2], s[3]));
}

// ---------------- K1: L2-normalize rows (f64-accumulated norm) -------------
__global__ __launch_bounds__(256) void norm_rows(const float* __restrict__ src,
                                                 float* __restrict__ dst_f32,
                                                 bf16_t* __restrict__ dst_bf,
                                                 int n_valid, int n_total) {
  int row  = blockIdx.x * 4 + (threadIdx.x >> 6);
  int lane = threadIdx.x & 63;
  if (row >= n_total) return;
  if (row >= n_valid) {
    if (dst_bf) {
      bf16_t* drow = dst_bf + (size_t)row * D;
      bf16x4 z = {(bf16_t)0.f, (bf16_t)0.f, (bf16_t)0.f, (bf16_t)0.f};
#pragma unroll
      for (int j = 0; j < 3; j++) *(bf16x4*)(drow + 4 * (lane + 64 * j)) = z;
    }
    return;
  }
  const float4* s = (const float4*)(src + (size_t)row * D);
  float4 v[3];
  double ss = 0.0;
#pragma unroll
  for (int j = 0; j < 3; j++) {
    v[j] = s[lane + 64 * j];
    ss += (double)v[j].x * v[j].x + (double)v[j].y * v[j].y +
          (double)v[j].z * v[j].z + (double)v[j].w * v[j].w;
  }
#pragma unroll
  for (int m = 32; m; m >>= 1) ss += __shfl_xor(ss, m);
  double inv = 1.0 / fmax(sqrt(ss), 1e-12);
  float4 o[3];
#pragma unroll
  for (int j = 0; j < 3; j++) {
    o[j].x = (float)((double)v[j].x * inv);
    o[j].y = (float)((double)v[j].y * inv);
    o[j].z = (float)((double)v[j].z * inv);
    o[j].w = (float)((double)v[j].w * inv);
  }
  if (dst_f32) {
    float* drow = dst_f32 + (size_t)row * D;
#pragma unroll
    for (int j = 0; j < 3; j++) ((float4*)drow)[lane + 64 * j] = o[j];
  }
  if (dst_bf) {
    bf16_t* drow = dst_bf + (size_t)row * D;
#pragma unroll
    for (int j = 0; j < 3; j++) {
      bf16x4 ob;
      ob[0] = (bf16_t)o[j].x; ob[1] = (bf16_t)o[j].y;
      ob[2] = (bf16_t)o[j].z; ob[3] = (bf16_t)o[j].w;
      *(bf16x4*)(drow + 4 * (lane + 64 * j)) = ob;
    }
  }
}

// ---------------- K2: max-sim GEMM v5 (round-2 shape + fused norm + 4 chains)
// 64 W-rows/block (4 waves x 16 rows, A register-resident). W read raw f32
// exactly once; f32 row-norm accumulated during A-load (scale-invariant bf16
// quantization); epilogue divides row-max by the norm. B = 16-proto bf16
// tiles double-buffered in LDS. 4 independent MFMA accumulator chains.
#define LDSROW 776  // 768 + 8 pad (bf16 units)

__global__ __launch_bounds__(256, 3) void maxsim_gemm(
    const float* __restrict__ W, const bf16_t* __restrict__ Tb,
    float* __restrict__ maxsim, int V, int U, int NT) {
  __shared__ __align__(16) bf16_t lds[2][16 * LDSROW];
  const int tid  = threadIdx.x;
  const int lane = tid & 63;
  const int r    = lane & 15;   // W row within tile (A), proto col (C)
  const int ks   = lane >> 4;   // k-slice 0..3
  const int rowbase = blockIdx.x * 64 + (tid >> 6) * 16;
  const int row0 = rowbase + r;
  const bool va  = row0 < V;

  // ---- A load (raw f32 -> bf16) + fused row-norm ----
  bf16x8 a[24];
  float ss = 0.f;
  {
    const float* p0 = W + (size_t)row0 * D + ks * 8;
#pragma unroll
    for (int kk = 0; kk < 24; kk++) {
      bf16x8 f;
      if (va) {
        float4 x = *(const float4*)(p0 + kk * 32);
        float4 y = *(const float4*)(p0 + kk * 32 + 4);
        ss += x.x * x.x + x.y * x.y + x.z * x.z + x.w * x.w +
              y.x * y.x + y.y * y.y + y.z * y.z + y.w * y.w;
        f[0] = (bf16_t)x.x; f[1] = (bf16_t)x.y; f[2] = (bf16_t)x.z; f[3] = (bf16_t)x.w;
        f[4] = (bf16_t)y.x; f[5] = (bf16_t)y.y; f[6] = (bf16_t)y.z; f[7] = (bf16_t)y.w;
      } else {
#pragma unroll
        for (int e = 0; e < 8; e++) f[e] = (bf16_t)0.f;
      }
      a[kk] = f;
    }
  }
  ss += __shfl_xor(ss, 16);
  ss += __shfl_xor(ss, 32);
  const double inv = 1.0 / fmax(sqrt((double)ss), 1e-12);

  auto stage = [&](int buf, int nt) {
    const ulonglong2* src = (const ulonglong2*)(Tb + (size_t)nt * 16 * D);
#pragma unroll
    for (int j = 0; j < 6; j++) {
      int c = tid + j * 256;        // 1536 x 16B chunks
      int rr = c / 96, w = c % 96;  // 96 chunks per row
      *(ulonglong2*)&lds[buf][rr * LDSROW + w * 8] = src[c];
    }
  };

  f32x4 mx = {-1e30f, -1e30f, -1e30f, -1e30f};
  stage(0, 0);
  for (int nt = 0; nt < NT; nt++) {
    __syncthreads();
    if (nt + 1 < NT) stage((nt + 1) & 1, nt + 1);
    f32x4 ac0 = {0.f,0.f,0.f,0.f}, ac1 = {0.f,0.f,0.f,0.f};
    f32x4 ac2 = {0.f,0.f,0.f,0.f}, ac3 = {0.f,0.f,0.f,0.f};
    const bf16_t* brow = &lds[nt & 1][r * LDSROW + ks * 8];
#pragma unroll
    for (int kk = 0; kk < 24; kk += 4) {
      bf16x8 b0 = *(const bf16x8*)(brow + kk * 32);
      bf16x8 b1 = *(const bf16x8*)(brow + kk * 32 + 32);
      bf16x8 b2 = *(const bf16x8*)(brow + kk * 32 + 64);
      bf16x8 b3 = *(const bf16x8*)(brow + kk * 32 + 96);
      ac0 = __builtin_amdgcn_mfma_f32_16x16x32_bf16(a[kk],     b0, ac0, 0, 0, 0);
      ac1 = __builtin_amdgcn_mfma_f32_16x16x32_bf16(a[kk + 1], b1, ac1, 0, 0, 0);
      ac2 = __builtin_amdgcn_mfma_f32_16x16x32_bf16(a[kk + 2], b2, ac2, 0, 0, 0);
      ac3 = __builtin_amdgcn_mfma_f32_16x16x32_bf16(a[kk + 3], b3, ac3, 0, 0, 0);
    }
    if (nt * 16 + r < U) {
#pragma unroll
      for (int j = 0; j < 4; j++)
        mx[j] = fmaxf(mx[j], (ac0[j] + ac1[j]) + (ac2[j] + ac3[j]));
    }
  }
  // reduce across the 16 proto-lanes (C layout: col=lane&15, row=ks*4+j)
#pragma unroll
  for (int m = 1; m < 16; m <<= 1) {
#pragma unroll
    for (int j = 0; j < 4; j++) mx[j] = fmaxf(mx[j], __shfl_xor(mx[j], m));
  }
#pragma unroll
  for (int j = 0; j < 4; j++) {
    int rr = ks * 4 + j;
    double iv = __shfl(inv, rr);  // row rowbase+rr's norm lives in lane rr
    if (r == 0 && rowbase + rr < V)
      maxsim[rowbase + rr] = (float)((double)mx[j] * iv);
  }
}

// ---------------- K3: approx sim GEMM (bf16 MFMA) ---------------------------
__global__ __launch_bounds__(256) void simf_gemm(const float* __restrict__ SUPn,
                                                 const bf16_t* __restrict__ TSb,
                                                 float* __restrict__ sim,
                                                 int Q, int ld, int NTB) {
  __shared__ __align__(16) bf16_t lds[2][16 * LDSROW];
  const int tid  = threadIdx.x;
  const int lane = tid & 63;
  const int rowbase = blockIdx.x * 64 + (tid >> 6) * 16;
  const int arow_i  = rowbase + (lane & 15);

  bf16x8 a[24];
  if (arow_i < Q) {
    const float* ar = SUPn + (size_t)arow_i * D + ((lane >> 4) * 8);
#pragma unroll
    for (int kk = 0; kk < 24; kk++) {
      float4 x = *(const float4*)(ar + kk * 32);
      float4 y = *(const float4*)(ar + kk * 32 + 4);
      bf16x8 f;
      f[0] = (bf16_t)x.x; f[1] = (bf16_t)x.y; f[2] = (bf16_t)x.z; f[3] = (bf16_t)x.w;
      f[4] = (bf16_t)y.x; f[5] = (bf16_t)y.y; f[6] = (bf16_t)y.z; f[7] = (bf16_t)y.w;
      a[kk] = f;
    }
  } else {
#pragma unroll
    for (int kk = 0; kk < 24; kk++) {
      bf16x8 f;
#pragma unroll
      for (int e = 0; e < 8; e++) f[e] = (bf16_t)0.f;
      a[kk] = f;
    }
  }

  auto stage = [&](int buf, int nt) {
    const ulonglong2* src = (const ulonglong2*)(TSb + (size_t)nt * 16 * D);
#pragma unroll
    for (int j = 0; j < 6; j++) {
      int c = tid + j * 256;
      int rr = c / 96, w = c % 96;
      *(ulonglong2*)&lds[buf][rr * LDSROW + w * 8] = src[c];
    }
  };

  stage(0, 0);
  for (int nt = 0; nt < NTB; nt++) {
    __syncthreads();
    if (nt + 1 < NTB) stage((nt + 1) & 1, nt + 1);
    f32x4 acc = {0.f, 0.f, 0.f, 0.f};
    const bf16_t* brow = &lds[nt & 1][(lane & 15) * LDSROW + ((lane >> 4) * 8)];
#pragma unroll
    for (int kk = 0; kk < 24; kk++) {
      bf16x8 b = *(const bf16x8*)(brow + kk * 32);
      acc = __builtin_amdgcn_mfma_f32_16x16x32_bf16(a[kk], b, acc, 0, 0, 0);
    }
    const int bcol = nt * 16 + (lane & 15);
    const int q0   = rowbase + ((lane >> 4) << 2);
    float* dst = sim + (size_t)bcol * ld + q0;
    if (q0 + 3 < Q) {
      *(f32x4*)dst = acc;
    } else {
#pragma unroll
      for (int j = 0; j < 4; j++)
        if (q0 + j < Q) dst[j] = acc[j];
    }
  }
}

// ---------------- K4: per-row top-16 on f32 sims (packed u64 keys) ----------
__device__ inline unsigned long long pack_key(float v, int q) {
  unsigned u = __float_as_uint(v);
  u = (u & 0x80000000u) ? ~u : (u | 0x80000000u);  // order-preserving map
  return ((unsigned long long)u << 32) | (unsigned)(0xFFFFFFFFu - (unsigned)q);
}

__global__ __launch_bounds__(256) void topk16_f32(const float* __restrict__ sim,
                                                  int* __restrict__ cand,
                                                  int Q, int ld) {
  __shared__ unsigned long long sk[256][16];
  const int b = blockIdx.x, tid = threadIdx.x;
  const float* row = sim + (size_t)b * ld;
  unsigned long long best[16];
#pragma unroll
  for (int k = 0; k < 16; k++) best[k] = 0ull;
  for (int q = tid; q < Q; q += 256) {
    unsigned long long key = pack_key(row[q], q);
    if (key > best[15]) {
      best[15] = key;
      for (int k = 15; k > 0; k--) {
        if (best[k] > best[k - 1]) {
          unsigned long long t = best[k]; best[k] = best[k - 1]; best[k - 1] = t;
        } else break;
      }
    }
  }
#pragma unroll
  for (int k = 0; k < 16; k++) sk[tid][k] = best[k];
  for (int stride = 128; stride >= 1; stride >>= 1) {
    __syncthreads();
    if (tid < stride) {
      unsigned long long out[16];
      int pa = 0, pb = 0;
#pragma unroll
      for (int k = 0; k < 16; k++) {
        unsigned long long va = sk[tid][pa], vb = sk[tid + stride][pb];
        if (va >= vb) { out[k] = va; pa++; }
        else          { out[k] = vb; pb++; }
      }
#pragma unroll
      for (int k = 0; k < 16; k++) sk[tid][k] = out[k];
    }
  }
  __syncthreads();
  if (tid < 16)
    cand[b * 16 + tid] = (int)(0xFFFFFFFFu - (unsigned)(sk[0][tid] & 0xFFFFFFFFull));
}

// ---------------- K5: exact f64 rescore of 16 candidates -> top-8 ----------
__global__ __launch_bounds__(256) void rescore(const float* __restrict__ SUPn,
                                               const float* __restrict__ TSn,
                                               const int* __restrict__ cand,
                                               int* __restrict__ topk) {
  __shared__ float tsrow[D];
  __shared__ double sval[16];
  __shared__ int    sidx[16];
  const int b = blockIdx.x, tid = threadIdx.x;
  const int lane = tid & 63, w = tid >> 6;
#pragma unroll
  for (int j = 0; j < 3; j++) tsrow[tid + 256 * j] = TSn[(size_t)b * D + tid + 256 * j];
  __syncthreads();
  for (int c = w; c < 16; c += 4) {
    int q = cand[b * 16 + c];
    const float* sr = SUPn + (size_t)q * D;
    double dot = 0.0;
#pragma unroll
    for (int i = 0; i < 12; i++)
      dot += (double)sr[lane + 64 * i] * (double)tsrow[lane + 64 * i];
#pragma unroll
    for (int m = 32; m; m >>= 1) dot += __shfl_xor(dot, m);
    if (lane == 0) { sval[c] = dot; sidx[c] = q; }
  }
  __syncthreads();
  if (tid == 0) {
    for (int i = 1; i < 16; i++) {
      double v = sval[i]; int ix = sidx[i];
      int j = i - 1;
      while (j >= 0 && (sval[j] < v || (sval[j] == v && sidx[j] > ix))) {
        sval[j + 1] = sval[j]; sidx[j + 1] = sidx[j]; j--;
      }
      sval[j + 1] = v; sidx[j + 1] = ix;
    }
#pragma unroll
    for (int k = 0; k < 8; k++) topk[b * 8 + k] = sidx[k];
  }
}

// ---------------- K6: gather rows to output + positive + pos_sim -----------
__global__ __launch_bounds__(256) void gather_pos(const float* __restrict__ SUPn,
                                                  const float* __restrict__ TSn,
                                                  const int* __restrict__ topk,
                                                  float* __restrict__ out,
                                                  double* __restrict__ pos_sim, int Q) {
  __shared__ int idx[8];
  __shared__ double red[4];
  const int b = blockIdx.x, tid = threadIdx.x;
  if (tid < 8) idx[tid] = topk[b * 8 + tid];
  __syncthreads();
  float mean[3] = {0.f, 0.f, 0.f};
#pragma unroll
  for (int k = 0; k < 8; k++) {
    const float* sr = SUPn + (size_t)idx[k] * D;
    float* orow = out + ((size_t)b * 8 + k) * D;
#pragma unroll
    for (int j = 0; j < 3; j++) {
      float x = sr[tid + 256 * j];
      orow[tid + 256 * j] = x;
      mean[j] += x;
    }
  }
#pragma unroll
  for (int j = 0; j < 3; j++) mean[j] *= 0.125f;
  double ss = 0.0;
#pragma unroll
  for (int j = 0; j < 3; j++) ss += (double)mean[j] * mean[j];
  ss = blk_sum(ss, red);
  double inv = 1.0 / fmax(sqrt(ss), 1e-12);
  double dot = 0.0;
#pragma unroll
  for (int j = 0; j < 3; j++)
    dot += (double)TSn[(size_t)b * D + tid + 256 * j] * ((double)mean[j] * inv);
  dot = blk_sum(dot, red);
  if (tid == 0) pos_sim[b] = dot / (double)0.07f;
}

// ---------------- K7: per-row NNCL logsumexp --------------------------------
__global__ __launch_bounds__(256) void nncl_rows(const float* __restrict__ TSn,
                                                 const double* __restrict__ pos_sim,
                                                 double* __restrict__ row_loss) {
  __shared__ float tsb[D];
  __shared__ double red[4];
  const int b = blockIdx.x, c = threadIdx.x;
#pragma unroll
  for (int j = 0; j < 3; j++) tsb[c + 256 * j] = TSn[(size_t)b * D + c + 256 * j];
  __syncthreads();
  const float* tc = TSn + (size_t)c * D;
  double dot = 0.0;
  for (int e = 0; e < D; e += 4) {
    float4 t4 = *(const float4*)(tc + e);
    dot += (double)tsb[e] * t4.x + (double)tsb[e + 1] * t4.y +
           (double)tsb[e + 2] * t4.z + (double)tsb[e + 3] * t4.w;
  }
  const bool diag = (c == b);
  double logit = dot / (double)0.07f;
  double p = pos_sim[b];
  double m = blk_max(diag ? -1e300 : logit, red);
  m = fmax(m, p);
  double term = diag ? 0.0 : exp(logit - m);
  double ssum = blk_sum(term, red);
  ssum += exp(p - m);
  if (c == 0) row_loss[b] = (log(ssum) + m) - p;
}

// ---------------- K8: finalize scalars --------------------------------------
__global__ __launch_bounds__(256) void finalize(const float* __restrict__ maxsim,
                                                const double* __restrict__ row_loss,
                                                float* __restrict__ d_out, int out_size,
                                                int V, int B) {
  __shared__ double red[4];
  const int tid = threadIdx.x;
  double s1 = 0.0;
  for (int v = tid; v < V; v += 256) s1 += 2.0 - 2.0 * (double)maxsim[v];
  s1 = blk_sum(s1, red);
  __syncthreads();
  double s2 = 0.0;
  for (int b = tid; b < B; b += 256) s2 += row_loss[b];
  s2 = blk_sum(s2, red);
  if (tid == 0) {
    d_out[out_size - 2] = (float)(s1 / ((double)V * (double)D));
    d_out[out_size - 1] = (float)(s2 / (double)B);
  }
}

// ---------------- host launcher ---------------------------------------------
extern "C" void kernel_launch(void* const* d_in, const int* in_sizes, int n_in,
                              void* d_out, int out_size, void* d_ws, size_t ws_size,
                              hipStream_t stream) {
  const float* TS  = (const float*)d_in[0];
  const float* W   = (const float*)d_in[1];
  const float* T   = (const float*)d_in[2];
  const float* SUP = (const float*)d_in[3];
  const int B = in_sizes[0] / D;   // 256
  const int V = in_sizes[1] / D;   // 50257
  const int U = in_sizes[2] / D;   // 1000
  const int Q = in_sizes[3] / D;   // 10000
  const int NT   = (U + 15) / 16;  // 63
  const int UPAD = NT * 16;        // 1008
  const int VPAD = (V + 63) & ~63; // 50304
  const int QPAD = (Q + 63) & ~63; // 10048
  const int NTB  = B / 16;         // 16

  char* ws = (char*)d_ws;
  size_t off = 0;
  auto alloc = [&](size_t bytes) -> char* {
    char* p = ws + off;
    off = (off + bytes + 255) & ~(size_t)255;
    return p;
  };
  bf16_t* t_bf   = (bf16_t*)alloc((size_t)UPAD * D * 2);
  float*  maxsim = (float*) alloc((size_t)VPAD * 4);
  float*  ts_n   = (float*) alloc((size_t)B * D * 4);
  bf16_t* ts_bf  = (bf16_t*)alloc((size_t)B * D * 2);
  float*  sup_n  = (float*) alloc((size_t)Q * D * 4);
  float*  simf   = (float*) alloc((size_t)B * QPAD * 4);
  int*    cand   = (int*)   alloc((size_t)B * 16 * 4);
  int*    tki    = (int*)   alloc((size_t)B * 8 * 4);
  double* psim   = (double*)alloc((size_t)B * 8);
  double* rloss  = (double*)alloc((size_t)B * 8);
  (void)ws_size; (void)n_in;

  norm_rows<<<UPAD / 4, 256, 0, stream>>>(T,   nullptr, t_bf,  U, UPAD);
  norm_rows<<<B    / 4, 256, 0, stream>>>(TS,  ts_n,  ts_bf,   B, B);
  norm_rows<<<(Q + 3) / 4, 256, 0, stream>>>(SUP, sup_n, nullptr, Q, Q);

  maxsim_gemm<<<VPAD / 64, 256, 0, stream>>>(W, t_bf, maxsim, V, U, NT);

  simf_gemm<<<QPAD / 64, 256, 0, stream>>>(sup_n, ts_bf, simf, Q, QPAD, NTB);
  topk16_f32<<<B, 256, 0, stream>>>(simf, cand, Q, QPAD);
  rescore<<<B, 256, 0, stream>>>(sup_n, ts_n, cand, tki);

  gather_pos<<<B, 256, 0, stream>>>(sup_n, ts_n, tki, (float*)d_out, psim, Q);
  nncl_rows<<<B, 256, 0, stream>>>(ts_n, psim, rloss);
  finalize<<<1, 256, 0, stream>>>(maxsim, rloss, (float*)d_out, out_size, V, B);
}

// Round 6
// 304.895 us; speedup vs baseline: 1.5125x; 1.1242x over previous
//
#include <hip/hip_runtime.h>
#include <hip/hip_bf16.h>
#include <math.h>

typedef __bf16 bf16_t;
typedef __bf16 bf16x8 __attribute__((ext_vector_type(8)));
typedef __bf16 bf16x4 __attribute__((ext_vector_type(4)));
typedef float  f32x4  __attribute__((ext_vector_type(4)));
typedef long   i64_t;

#define D 768

// ---------------- block reduction helpers (blockDim == 256) ----------------
__device__ inline double blk_sum(double x, double* s) {
#pragma unroll
  for (int m = 32; m; m >>= 1) x += __shfl_xor(x, m);
  __syncthreads();
  if ((threadIdx.x & 63) == 0) s[threadIdx.x >> 6] = x;
  __syncthreads();
  return s[0] + s[1] + s[2] + s[3];
}

__device__ inline double blk_max(double x, double* s) {
#pragma unroll
  for (int m = 32; m; m >>= 1) x = fmax(x, __shfl_xor(x, m));
  __syncthreads();
  if ((threadIdx.x & 63) == 0) s[threadIdx.x >> 6] = x;
  __syncthreads();
  return fmax(fmax(s[0], s[1]), fmax(s[2], s[3]));
}

// ---------------- K1: L2-normalize rows (f64-accumulated norm) -------------
// Optional outputs: f32, bf16, fp8-e4m3 (packed u32, scaled by fp8_scale).
__global__ __launch_bounds__(256) void norm_rows(const float* __restrict__ src,
                                                 float* __restrict__ dst_f32,
                                                 bf16_t* __restrict__ dst_bf,
                                                 unsigned int* __restrict__ dst_fp8,
                                                 float fp8_scale,
                                                 int n_valid, int n_total) {
  int row  = blockIdx.x * 4 + (threadIdx.x >> 6);
  int lane = threadIdx.x & 63;
  if (row >= n_total) return;
  if (row >= n_valid) {
    if (dst_bf) {
      bf16_t* drow = dst_bf + (size_t)row * D;
      bf16x4 z = {(bf16_t)0.f, (bf16_t)0.f, (bf16_t)0.f, (bf16_t)0.f};
#pragma unroll
      for (int j = 0; j < 3; j++) *(bf16x4*)(drow + 4 * (lane + 64 * j)) = z;
    }
    if (dst_fp8) {
      unsigned int* drow = dst_fp8 + (size_t)row * (D / 4);
#pragma unroll
      for (int j = 0; j < 3; j++) drow[lane + 64 * j] = 0u;
    }
    return;
  }
  const float4* s = (const float4*)(src + (size_t)row * D);
  float4 v[3];
  double ss = 0.0;
#pragma unroll
  for (int j = 0; j < 3; j++) {
    v[j] = s[lane + 64 * j];
    ss += (double)v[j].x * v[j].x + (double)v[j].y * v[j].y +
          (double)v[j].z * v[j].z + (double)v[j].w * v[j].w;
  }
#pragma unroll
  for (int m = 32; m; m >>= 1) ss += __shfl_xor(ss, m);
  double inv = 1.0 / fmax(sqrt(ss), 1e-12);
  float4 o[3];
#pragma unroll
  for (int j = 0; j < 3; j++) {
    o[j].x = (float)((double)v[j].x * inv);
    o[j].y = (float)((double)v[j].y * inv);
    o[j].z = (float)((double)v[j].z * inv);
    o[j].w = (float)((double)v[j].w * inv);
  }
  if (dst_f32) {
    float* drow = dst_f32 + (size_t)row * D;
#pragma unroll
    for (int j = 0; j < 3; j++) ((float4*)drow)[lane + 64 * j] = o[j];
  }
  if (dst_bf) {
    bf16_t* drow = dst_bf + (size_t)row * D;
#pragma unroll
    for (int j = 0; j < 3; j++) {
      bf16x4 ob;
      ob[0] = (bf16_t)o[j].x; ob[1] = (bf16_t)o[j].y;
      ob[2] = (bf16_t)o[j].z; ob[3] = (bf16_t)o[j].w;
      *(bf16x4*)(drow + 4 * (lane + 64 * j)) = ob;
    }
  }
  if (dst_fp8) {
    unsigned int* drow = dst_fp8 + (size_t)row * (D / 4);
#pragma unroll
    for (int j = 0; j < 3; j++) {
      float a0 = o[j].x * fp8_scale, a1 = o[j].y * fp8_scale;
      float a2 = o[j].z * fp8_scale, a3 = o[j].w * fp8_scale;
      int pk = __builtin_amdgcn_cvt_pk_fp8_f32(a0, a1, 0, false);
      pk = __builtin_amdgcn_cvt_pk_fp8_f32(a2, a3, pk, true);
      drow[lane + 64 * j] = (unsigned int)pk;
    }
  }
}

// ---------------- K2: max-sim GEMM v6 (fp8 MFMA, fused W norm) --------------
// 64 W-rows/block (4 waves x 16 rows). W read raw f32 once, quantized to
// e4m3 in registers (scale-invariant: final row-max divided by f32 norm).
// B = 16-proto fp8 tiles (T normalized x16) double-buffered in LDS; 512B
// ds_read_b64 per MFMA. 4 independent accumulator chains.
#define T8ROW 784  // 768 + 16 pad (bytes)

__global__ __launch_bounds__(256) void maxsim_gemm(
    const float* __restrict__ W, const unsigned char* __restrict__ T8,
    float* __restrict__ maxsim, int V, int U, int NT) {
  __shared__ __align__(16) unsigned char lds[2][16 * T8ROW];
  const int tid  = threadIdx.x;
  const int lane = tid & 63;
  const int r    = lane & 15;   // W row within tile (A), proto col (C)
  const int ks   = lane >> 4;   // k-slice 0..3
  const int rowbase = blockIdx.x * 64 + (tid >> 6) * 16;
  const int row0 = rowbase + r;
  const bool va  = row0 < V;

  // ---- A load (raw f32 -> e4m3) + fused row-norm ----
  i64_t a[24];
  float ss = 0.f;
  {
    const float* p0 = W + (size_t)row0 * D + ks * 8;
#pragma unroll
    for (int kk = 0; kk < 24; kk++) {
      i64_t frag = 0;
      if (va) {
        float4 x = *(const float4*)(p0 + kk * 32);
        float4 y = *(const float4*)(p0 + kk * 32 + 4);
        ss += x.x * x.x + x.y * x.y + x.z * x.z + x.w * x.w +
              y.x * y.x + y.y * y.y + y.z * y.z + y.w * y.w;
        int lo = __builtin_amdgcn_cvt_pk_fp8_f32(x.x, x.y, 0, false);
        lo = __builtin_amdgcn_cvt_pk_fp8_f32(x.z, x.w, lo, true);
        int hi = __builtin_amdgcn_cvt_pk_fp8_f32(y.x, y.y, 0, false);
        hi = __builtin_amdgcn_cvt_pk_fp8_f32(y.z, y.w, hi, true);
        frag = ((i64_t)hi << 32) | (i64_t)(unsigned int)lo;
      }
      a[kk] = frag;
    }
  }
  ss += __shfl_xor(ss, 16);
  ss += __shfl_xor(ss, 32);
  const double inv = 1.0 / fmax(sqrt((double)ss), 1e-12);

  auto stage = [&](int buf, int nt) {
    const ulonglong2* src = (const ulonglong2*)(T8 + (size_t)nt * 16 * D);
#pragma unroll
    for (int j = 0; j < 3; j++) {
      int c = tid + j * 256;        // 768 x 16B chunks
      int rr = c / 48, w = c % 48;  // 48 chunks per row
      *(ulonglong2*)&lds[buf][rr * T8ROW + w * 16] = src[c];
    }
  };

  f32x4 mx = {-1e30f, -1e30f, -1e30f, -1e30f};
  stage(0, 0);
  for (int nt = 0; nt < NT; nt++) {
    __syncthreads();
    if (nt + 1 < NT) stage((nt + 1) & 1, nt + 1);
    f32x4 ac0 = {0.f,0.f,0.f,0.f}, ac1 = {0.f,0.f,0.f,0.f};
    f32x4 ac2 = {0.f,0.f,0.f,0.f}, ac3 = {0.f,0.f,0.f,0.f};
    const unsigned char* brow = &lds[nt & 1][r * T8ROW + ks * 8];
#pragma unroll
    for (int kk = 0; kk < 24; kk += 4) {
      i64_t b0 = *(const i64_t*)(brow + kk * 32);
      i64_t b1 = *(const i64_t*)(brow + kk * 32 + 32);
      i64_t b2 = *(const i64_t*)(brow + kk * 32 + 64);
      i64_t b3 = *(const i64_t*)(brow + kk * 32 + 96);
      ac0 = __builtin_amdgcn_mfma_f32_16x16x32_fp8_fp8(a[kk],     b0, ac0, 0, 0, 0);
      ac1 = __builtin_amdgcn_mfma_f32_16x16x32_fp8_fp8(a[kk + 1], b1, ac1, 0, 0, 0);
      ac2 = __builtin_amdgcn_mfma_f32_16x16x32_fp8_fp8(a[kk + 2], b2, ac2, 0, 0, 0);
      ac3 = __builtin_amdgcn_mfma_f32_16x16x32_fp8_fp8(a[kk + 3], b3, ac3, 0, 0, 0);
    }
    if (nt * 16 + r < U) {
#pragma unroll
      for (int j = 0; j < 4; j++)
        mx[j] = fmaxf(mx[j], (ac0[j] + ac1[j]) + (ac2[j] + ac3[j]));
    }
  }
  // reduce across the 16 proto-lanes (C layout: col=lane&15, row=ks*4+j)
#pragma unroll
  for (int m = 1; m < 16; m <<= 1) {
#pragma unroll
    for (int j = 0; j < 4; j++) mx[j] = fmaxf(mx[j], __shfl_xor(mx[j], m));
  }
#pragma unroll
  for (int j = 0; j < 4; j++) {
    int rr = ks * 4 + j;
    double iv = __shfl(inv, rr);  // row rowbase+rr's norm lives in lane rr
    if (r == 0 && rowbase + rr < V)
      maxsim[rowbase + rr] = (float)((double)mx[j] * iv * (1.0 / 16.0));
  }
}

// ---------------- K3: approx sim GEMM (bf16 MFMA) ---------------------------
#define LDSROW 776  // 768 + 8 pad (bf16 units)

__global__ __launch_bounds__(256) void simf_gemm(const float* __restrict__ SUPn,
                                                 const bf16_t* __restrict__ TSb,
                                                 float* __restrict__ sim,
                                                 int Q, int ld, int NTB) {
  __shared__ __align__(16) bf16_t lds[2][16 * LDSROW];
  const int tid  = threadIdx.x;
  const int lane = tid & 63;
  const int rowbase = blockIdx.x * 64 + (tid >> 6) * 16;
  const int arow_i  = rowbase + (lane & 15);

  bf16x8 a[24];
  if (arow_i < Q) {
    const float* ar = SUPn + (size_t)arow_i * D + ((lane >> 4) * 8);
#pragma unroll
    for (int kk = 0; kk < 24; kk++) {
      float4 x = *(const float4*)(ar + kk * 32);
      float4 y = *(const float4*)(ar + kk * 32 + 4);
      bf16x8 f;
      f[0] = (bf16_t)x.x; f[1] = (bf16_t)x.y; f[2] = (bf16_t)x.z; f[3] = (bf16_t)x.w;
      f[4] = (bf16_t)y.x; f[5] = (bf16_t)y.y; f[6] = (bf16_t)y.z; f[7] = (bf16_t)y.w;
      a[kk] = f;
    }
  } else {
#pragma unroll
    for (int kk = 0; kk < 24; kk++) {
      bf16x8 f;
#pragma unroll
      for (int e = 0; e < 8; e++) f[e] = (bf16_t)0.f;
      a[kk] = f;
    }
  }

  auto stage = [&](int buf, int nt) {
    const ulonglong2* src = (const ulonglong2*)(TSb + (size_t)nt * 16 * D);
#pragma unroll
    for (int j = 0; j < 6; j++) {
      int c = tid + j * 256;
      int rr = c / 96, w = c % 96;
      *(ulonglong2*)&lds[buf][rr * LDSROW + w * 8] = src[c];
    }
  };

  stage(0, 0);
  for (int nt = 0; nt < NTB; nt++) {
    __syncthreads();
    if (nt + 1 < NTB) stage((nt + 1) & 1, nt + 1);
    f32x4 acc = {0.f, 0.f, 0.f, 0.f};
    const bf16_t* brow = &lds[nt & 1][(lane & 15) * LDSROW + ((lane >> 4) * 8)];
#pragma unroll
    for (int kk = 0; kk < 24; kk++) {
      bf16x8 b = *(const bf16x8*)(brow + kk * 32);
      acc = __builtin_amdgcn_mfma_f32_16x16x32_bf16(a[kk], b, acc, 0, 0, 0);
    }
    const int bcol = nt * 16 + (lane & 15);
    const int q0   = rowbase + ((lane >> 4) << 2);
    float* dst = sim + (size_t)bcol * ld + q0;
    if (q0 + 3 < Q) {
      *(f32x4*)dst = acc;
    } else {
#pragma unroll
      for (int j = 0; j < 4; j++)
        if (q0 + j < Q) dst[j] = acc[j];
    }
  }
}

// ---------------- K4: per-row top-16 + exact f64 rescore -> top-8 ----------
__device__ inline unsigned long long pack_key(float v, int q) {
  unsigned u = __float_as_uint(v);
  u = (u & 0x80000000u) ? ~u : (u | 0x80000000u);  // order-preserving map
  return ((unsigned long long)u << 32) | (unsigned)(0xFFFFFFFFu - (unsigned)q);
}

__global__ __launch_bounds__(256) void topk_rescore(const float* __restrict__ sim,
                                                    const float* __restrict__ SUPn,
                                                    const float* __restrict__ TSn,
                                                    int* __restrict__ topk,
                                                    int Q, int ld) {
  __shared__ unsigned long long sk[256][16];
  __shared__ float tsrow[D];
  __shared__ double sval[16];
  __shared__ int    sidx[16];
  const int b = blockIdx.x, tid = threadIdx.x;
#pragma unroll
  for (int j = 0; j < 3; j++) tsrow[tid + 256 * j] = TSn[(size_t)b * D + tid + 256 * j];

  const float* row = sim + (size_t)b * ld;
  unsigned long long best[16];
#pragma unroll
  for (int k = 0; k < 16; k++) best[k] = 0ull;
  for (int q = tid; q < Q; q += 256) {
    unsigned long long key = pack_key(row[q], q);
    if (key > best[15]) {
      best[15] = key;
      for (int k = 15; k > 0; k--) {
        if (best[k] > best[k - 1]) {
          unsigned long long t = best[k]; best[k] = best[k - 1]; best[k - 1] = t;
        } else break;
      }
    }
  }
#pragma unroll
  for (int k = 0; k < 16; k++) sk[tid][k] = best[k];
  for (int stride = 128; stride >= 1; stride >>= 1) {
    __syncthreads();
    if (tid < stride) {
      unsigned long long out[16];
      int pa = 0, pb = 0;
#pragma unroll
      for (int k = 0; k < 16; k++) {
        unsigned long long va = sk[tid][pa], vb = sk[tid + stride][pb];
        if (va >= vb) { out[k] = va; pa++; }
        else          { out[k] = vb; pb++; }
      }
#pragma unroll
      for (int k = 0; k < 16; k++) sk[tid][k] = out[k];
    }
  }
  __syncthreads();

  // exact f64 rescore of the 16 candidates (1 wave each, 4 waves x 4 rounds)
  const int lane = tid & 63, w = tid >> 6;
  for (int c = w; c < 16; c += 4) {
    int q = (int)(0xFFFFFFFFu - (unsigned)(sk[0][c] & 0xFFFFFFFFull));
    const float* sr = SUPn + (size_t)q * D;
    double dot = 0.0;
#pragma unroll
    for (int i = 0; i < 12; i++)
      dot += (double)sr[lane + 64 * i] * (double)tsrow[lane + 64 * i];
#pragma unroll
    for (int m = 32; m; m >>= 1) dot += __shfl_xor(dot, m);
    if (lane == 0) { sval[c] = dot; sidx[c] = q; }
  }
  __syncthreads();
  if (tid == 0) {
    for (int i = 1; i < 16; i++) {
      double v = sval[i]; int ix = sidx[i];
      int j = i - 1;
      while (j >= 0 && (sval[j] < v || (sval[j] == v && sidx[j] > ix))) {
        sval[j + 1] = sval[j]; sidx[j + 1] = sidx[j]; j--;
      }
      sval[j + 1] = v; sidx[j + 1] = ix;
    }
#pragma unroll
    for (int k = 0; k < 8; k++) topk[b * 8 + k] = sidx[k];
  }
}

// ---------------- K5: gather + positive + pos_sim + NNCL row loss ----------
__global__ __launch_bounds__(256) void gather_nncl(const float* __restrict__ SUPn,
                                                   const float* __restrict__ TSn,
                                                   const int* __restrict__ topk,
                                                   float* __restrict__ out,
                                                   double* __restrict__ row_loss) {
  __shared__ int idx[8];
  __shared__ double red[4];
  __shared__ float tsb[D];
  const int b = blockIdx.x, tid = threadIdx.x;
  if (tid < 8) idx[tid] = topk[b * 8 + tid];
  float tsv[3];
#pragma unroll
  for (int j = 0; j < 3; j++) {
    tsv[j] = TSn[(size_t)b * D + tid + 256 * j];
    tsb[tid + 256 * j] = tsv[j];
  }
  __syncthreads();
  float mean[3] = {0.f, 0.f, 0.f};
#pragma unroll
  for (int k = 0; k < 8; k++) {
    const float* sr = SUPn + (size_t)idx[k] * D;
    float* orow = out + ((size_t)b * 8 + k) * D;
#pragma unroll
    for (int j = 0; j < 3; j++) {
      float x = sr[tid + 256 * j];
      orow[tid + 256 * j] = x;
      mean[j] += x;
    }
  }
#pragma unroll
  for (int j = 0; j < 3; j++) mean[j] *= 0.125f;
  double ss = 0.0;
#pragma unroll
  for (int j = 0; j < 3; j++) ss += (double)mean[j] * mean[j];
  ss = blk_sum(ss, red);
  double inv = 1.0 / fmax(sqrt(ss), 1e-12);
  double dot = 0.0;
#pragma unroll
  for (int j = 0; j < 3; j++)
    dot += (double)tsv[j] * ((double)mean[j] * inv);
  dot = blk_sum(dot, red);
  const double p = dot / (double)0.07f;

  // ---- NNCL logsumexp over columns c = tid ----
  const float* tc = TSn + (size_t)tid * D;
  double dot2 = 0.0;
  for (int e = 0; e < D; e += 4) {
    float4 t4 = *(const float4*)(tc + e);
    dot2 += (double)tsb[e] * t4.x + (double)tsb[e + 1] * t4.y +
            (double)tsb[e + 2] * t4.z + (double)tsb[e + 3] * t4.w;
  }
  const bool diag = (tid == b);
  double logit = dot2 / (double)0.07f;
  double m = blk_max(diag ? -1e300 : logit, red);
  m = fmax(m, p);
  double term = diag ? 0.0 : exp(logit - m);
  double ssum = blk_sum(term, red);
  ssum += exp(p - m);
  if (tid == 0) row_loss[b] = (log(ssum) + m) - p;
}

// ---------------- K6: finalize scalars --------------------------------------
__global__ __launch_bounds__(256) void finalize(const float* __restrict__ maxsim,
                                                const double* __restrict__ row_loss,
                                                float* __restrict__ d_out, int out_size,
                                                int V, int B) {
  __shared__ double red[4];
  const int tid = threadIdx.x;
  double s1 = 0.0;
  for (int v = tid; v < V; v += 256) s1 += 2.0 - 2.0 * (double)maxsim[v];
  s1 = blk_sum(s1, red);
  __syncthreads();
  double s2 = 0.0;
  for (int b = tid; b < B; b += 256) s2 += row_loss[b];
  s2 = blk_sum(s2, red);
  if (tid == 0) {
    d_out[out_size - 2] = (float)(s1 / ((double)V * (double)D));
    d_out[out_size - 1] = (float)(s2 / (double)B);
  }
}

// ---------------- host launcher ---------------------------------------------
extern "C" void kernel_launch(void* const* d_in, const int* in_sizes, int n_in,
                              void* d_out, int out_size, void* d_ws, size_t ws_size,
                              hipStream_t stream) {
  const float* TS  = (const float*)d_in[0];
  const float* W   = (const float*)d_in[1];
  const float* T   = (const float*)d_in[2];
  const float* SUP = (const float*)d_in[3];
  const int B = in_sizes[0] / D;   // 256
  const int V = in_sizes[1] / D;   // 50257
  const int U = in_sizes[2] / D;   // 1000
  const int Q = in_sizes[3] / D;   // 10000
  const int NT   = (U + 15) / 16;  // 63
  const int UPAD = NT * 16;        // 1008
  const int VPAD = (V + 63) & ~63; // 50304
  const int QPAD = (Q + 63) & ~63; // 10048
  const int NTB  = B / 16;         // 16

  char* ws = (char*)d_ws;
  size_t off = 0;
  auto alloc = [&](size_t bytes) -> char* {
    char* p = ws + off;
    off = (off + bytes + 255) & ~(size_t)255;
    return p;
  };
  unsigned int* t8 = (unsigned int*)alloc((size_t)UPAD * D);  // fp8 bytes
  float*  maxsim = (float*) alloc((size_t)VPAD * 4);
  float*  ts_n   = (float*) alloc((size_t)B * D * 4);
  bf16_t* ts_bf  = (bf16_t*)alloc((size_t)B * D * 2);
  float*  sup_n  = (float*) alloc((size_t)Q * D * 4);
  float*  simf   = (float*) alloc((size_t)B * QPAD * 4);
  int*    tki    = (int*)   alloc((size_t)B * 8 * 4);
  double* rloss  = (double*)alloc((size_t)B * 8);
  (void)ws_size; (void)n_in;

  norm_rows<<<UPAD / 4, 256, 0, stream>>>(T, nullptr, nullptr, t8, 16.f, U, UPAD);
  norm_rows<<<B / 4, 256, 0, stream>>>(TS, ts_n, ts_bf, nullptr, 0.f, B, B);
  norm_rows<<<(Q + 3) / 4, 256, 0, stream>>>(SUP, sup_n, nullptr, nullptr, 0.f, Q, Q);

  maxsim_gemm<<<VPAD / 64, 256, 0, stream>>>(W, (const unsigned char*)t8,
                                             maxsim, V, U, NT);

  simf_gemm<<<QPAD / 64, 256, 0, stream>>>(sup_n, ts_bf, simf, Q, QPAD, NTB);
  topk_rescore<<<B, 256, 0, stream>>>(simf, sup_n, ts_n, tki, Q, QPAD);
  gather_nncl<<<B, 256, 0, stream>>>(sup_n, ts_n, tki, (float*)d_out, rloss);
  finalize<<<1, 256, 0, stream>>>(maxsim, rloss, (float*)d_out, out_size, V, B);
}

// Round 7
// 280.817 us; speedup vs baseline: 1.6421x; 1.0857x over previous
//
#include <hip/hip_runtime.h>
#include <hip/hip_bf16.h>
#include <math.h>

typedef __bf16 bf16_t;
typedef __bf16 bf16x8 __attribute__((ext_vector_type(8)));
typedef __bf16 bf16x4 __attribute__((ext_vector_type(4)));
typedef float  f32x4  __attribute__((ext_vector_type(4)));
typedef long   i64_t;

#define D 768

// ---------------- block reduction helpers (blockDim == 256) ----------------
__device__ inline double blk_sum(double x, double* s) {
#pragma unroll
  for (int m = 32; m; m >>= 1) x += __shfl_xor(x, m);
  __syncthreads();
  if ((threadIdx.x & 63) == 0) s[threadIdx.x >> 6] = x;
  __syncthreads();
  return s[0] + s[1] + s[2] + s[3];
}

__device__ inline double blk_max(double x, double* s) {
#pragma unroll
  for (int m = 32; m; m >>= 1) x = fmax(x, __shfl_xor(x, m));
  __syncthreads();
  if ((threadIdx.x & 63) == 0) s[threadIdx.x >> 6] = x;
  __syncthreads();
  return fmax(fmax(s[0], s[1]), fmax(s[2], s[3]));
}

// ---------------- K1: L2-normalize rows (f64-accumulated norm) -------------
// Optional outputs: f32, bf16, fp8-e4m3 (packed u32, scaled by fp8_scale).
__global__ __launch_bounds__(256) void norm_rows(const float* __restrict__ src,
                                                 float* __restrict__ dst_f32,
                                                 bf16_t* __restrict__ dst_bf,
                                                 unsigned int* __restrict__ dst_fp8,
                                                 float fp8_scale,
                                                 int n_valid, int n_total) {
  int row  = blockIdx.x * 4 + (threadIdx.x >> 6);
  int lane = threadIdx.x & 63;
  if (row >= n_total) return;
  if (row >= n_valid) {
    if (dst_bf) {
      bf16_t* drow = dst_bf + (size_t)row * D;
      bf16x4 z = {(bf16_t)0.f, (bf16_t)0.f, (bf16_t)0.f, (bf16_t)0.f};
#pragma unroll
      for (int j = 0; j < 3; j++) *(bf16x4*)(drow + 4 * (lane + 64 * j)) = z;
    }
    if (dst_fp8) {
      unsigned int* drow = dst_fp8 + (size_t)row * (D / 4);
#pragma unroll
      for (int j = 0; j < 3; j++) drow[lane + 64 * j] = 0u;
    }
    return;
  }
  const float4* s = (const float4*)(src + (size_t)row * D);
  float4 v[3];
  double ss = 0.0;
#pragma unroll
  for (int j = 0; j < 3; j++) {
    v[j] = s[lane + 64 * j];
    ss += (double)v[j].x * v[j].x + (double)v[j].y * v[j].y +
          (double)v[j].z * v[j].z + (double)v[j].w * v[j].w;
  }
#pragma unroll
  for (int m = 32; m; m >>= 1) ss += __shfl_xor(ss, m);
  double inv = 1.0 / fmax(sqrt(ss), 1e-12);
  float4 o[3];
#pragma unroll
  for (int j = 0; j < 3; j++) {
    o[j].x = (float)((double)v[j].x * inv);
    o[j].y = (float)((double)v[j].y * inv);
    o[j].z = (float)((double)v[j].z * inv);
    o[j].w = (float)((double)v[j].w * inv);
  }
  if (dst_f32) {
    float* drow = dst_f32 + (size_t)row * D;
#pragma unroll
    for (int j = 0; j < 3; j++) ((float4*)drow)[lane + 64 * j] = o[j];
  }
  if (dst_bf) {
    bf16_t* drow = dst_bf + (size_t)row * D;
#pragma unroll
    for (int j = 0; j < 3; j++) {
      bf16x4 ob;
      ob[0] = (bf16_t)o[j].x; ob[1] = (bf16_t)o[j].y;
      ob[2] = (bf16_t)o[j].z; ob[3] = (bf16_t)o[j].w;
      *(bf16x4*)(drow + 4 * (lane + 64 * j)) = ob;
    }
  }
  if (dst_fp8) {
    unsigned int* drow = dst_fp8 + (size_t)row * (D / 4);
#pragma unroll
    for (int j = 0; j < 3; j++) {
      float a0 = o[j].x * fp8_scale, a1 = o[j].y * fp8_scale;
      float a2 = o[j].z * fp8_scale, a3 = o[j].w * fp8_scale;
      int pk = __builtin_amdgcn_cvt_pk_fp8_f32(a0, a1, 0, false);
      pk = __builtin_amdgcn_cvt_pk_fp8_f32(a2, a3, pk, true);
      drow[lane + 64 * j] = (unsigned int)pk;
    }
  }
}

// ---------------- K2: max-sim GEMM v7 (fp8, U-split, swizzled LDS) ----------
// 64 W-rows/block, gridDim.y = 2 halves of the U tile range (latency hiding:
// 1572 blocks -> ~6 blocks/CU). W read raw f32, quantized e4m3 in regs
// (scale-invariant; row-max divided by f32 norm). T8 tiles staged in LDS
// with 16B-slot XOR swizzle ((row&7)<<4) -> uniform bank spread on the
// ds_read_b64 fragment reads. Partial maxes to maxpart[half][row].
__global__ __launch_bounds__(256) void maxsim_gemm(
    const float* __restrict__ W, const unsigned char* __restrict__ T8,
    float* __restrict__ maxpart, int V, int U, int NT, int vstride) {
  __shared__ __align__(16) unsigned char lds[2][16 * 768];
  const int tid  = threadIdx.x;
  const int lane = tid & 63;
  const int r    = lane & 15;   // W row within tile (A), proto col (C)
  const int ks   = lane >> 4;   // k-slice 0..3
  const int rowbase = blockIdx.x * 64 + (tid >> 6) * 16;
  const int row0 = rowbase + r;
  const bool va  = row0 < V;
  const int swzr = (r & 7) << 4;

  // ---- A load (raw f32 -> e4m3) + fused row-norm ----
  i64_t a[24];
  float ss = 0.f;
  {
    const float* p0 = W + (size_t)row0 * D + ks * 8;
#pragma unroll
    for (int kk = 0; kk < 24; kk++) {
      i64_t frag = 0;
      if (va) {
        float4 x = *(const float4*)(p0 + kk * 32);
        float4 y = *(const float4*)(p0 + kk * 32 + 4);
        ss += x.x * x.x + x.y * x.y + x.z * x.z + x.w * x.w +
              y.x * y.x + y.y * y.y + y.z * y.z + y.w * y.w;
        int lo = __builtin_amdgcn_cvt_pk_fp8_f32(x.x, x.y, 0, false);
        lo = __builtin_amdgcn_cvt_pk_fp8_f32(x.z, x.w, lo, true);
        int hi = __builtin_amdgcn_cvt_pk_fp8_f32(y.x, y.y, 0, false);
        hi = __builtin_amdgcn_cvt_pk_fp8_f32(y.z, y.w, hi, true);
        frag = ((i64_t)hi << 32) | (i64_t)(unsigned int)lo;
      }
      a[kk] = frag;
    }
  }
  ss += __shfl_xor(ss, 16);
  ss += __shfl_xor(ss, 32);
  const double inv = 1.0 / fmax(sqrt((double)ss), 1e-12);

  auto stage = [&](int buf, int nt) {
    const ulonglong2* src = (const ulonglong2*)(T8 + (size_t)nt * 16 * D);
#pragma unroll
    for (int j = 0; j < 3; j++) {
      int c = tid + j * 256;        // 768 x 16B chunks
      int rr = c / 48, w = c % 48;  // 48 chunks per row
      *(ulonglong2*)&lds[buf][rr * 768 + ((w * 16) ^ ((rr & 7) << 4))] = src[c];
    }
  };

  const int t0   = blockIdx.y * 32;           // this half's tile range
  const int tend = min(NT, t0 + 32);

  f32x4 mx = {-1e30f, -1e30f, -1e30f, -1e30f};
  stage(0, t0);
  for (int nt = t0; nt < tend; nt++) {
    __syncthreads();
    if (nt + 1 < tend) stage((nt + 1) & 1, nt + 1);
    f32x4 ac0 = {0.f,0.f,0.f,0.f}, ac1 = {0.f,0.f,0.f,0.f};
    f32x4 ac2 = {0.f,0.f,0.f,0.f}, ac3 = {0.f,0.f,0.f,0.f};
    const unsigned char* brow = &lds[nt & 1][r * 768];
#pragma unroll
    for (int kk = 0; kk < 24; kk += 4) {
      i64_t b0 = *(const i64_t*)(brow + (((kk + 0) * 32 + ks * 8) ^ swzr));
      i64_t b1 = *(const i64_t*)(brow + (((kk + 1) * 32 + ks * 8) ^ swzr));
      i64_t b2 = *(const i64_t*)(brow + (((kk + 2) * 32 + ks * 8) ^ swzr));
      i64_t b3 = *(const i64_t*)(brow + (((kk + 3) * 32 + ks * 8) ^ swzr));
      ac0 = __builtin_amdgcn_mfma_f32_16x16x32_fp8_fp8(a[kk],     b0, ac0, 0, 0, 0);
      ac1 = __builtin_amdgcn_mfma_f32_16x16x32_fp8_fp8(a[kk + 1], b1, ac1, 0, 0, 0);
      ac2 = __builtin_amdgcn_mfma_f32_16x16x32_fp8_fp8(a[kk + 2], b2, ac2, 0, 0, 0);
      ac3 = __builtin_amdgcn_mfma_f32_16x16x32_fp8_fp8(a[kk + 3], b3, ac3, 0, 0, 0);
    }
    if (nt * 16 + r < U) {
#pragma unroll
      for (int j = 0; j < 4; j++)
        mx[j] = fmaxf(mx[j], (ac0[j] + ac1[j]) + (ac2[j] + ac3[j]));
    }
  }
  // reduce across the 16 proto-lanes (C layout: col=lane&15, row=ks*4+j)
#pragma unroll
  for (int m = 1; m < 16; m <<= 1) {
#pragma unroll
    for (int j = 0; j < 4; j++) mx[j] = fmaxf(mx[j], __shfl_xor(mx[j], m));
  }
#pragma unroll
  for (int j = 0; j < 4; j++) {
    int rr = ks * 4 + j;
    double iv = __shfl(inv, rr);  // row rowbase+rr's norm lives in lane rr
    if (r == 0 && rowbase + rr < V)
      maxpart[blockIdx.y * vstride + rowbase + rr] =
          (float)((double)mx[j] * iv * (1.0 / 16.0));
  }
}

// ---------------- K3: approx sim GEMM (bf16 MFMA) ---------------------------
#define LDSROW 776  // 768 + 8 pad (bf16 units)

__global__ __launch_bounds__(256) void simf_gemm(const float* __restrict__ SUPn,
                                                 const bf16_t* __restrict__ TSb,
                                                 float* __restrict__ sim,
                                                 int Q, int ld, int NTB) {
  __shared__ __align__(16) bf16_t lds[2][16 * LDSROW];
  const int tid  = threadIdx.x;
  const int lane = tid & 63;
  const int rowbase = blockIdx.x * 64 + (tid >> 6) * 16;
  const int arow_i  = rowbase + (lane & 15);

  bf16x8 a[24];
  if (arow_i < Q) {
    const float* ar = SUPn + (size_t)arow_i * D + ((lane >> 4) * 8);
#pragma unroll
    for (int kk = 0; kk < 24; kk++) {
      float4 x = *(const float4*)(ar + kk * 32);
      float4 y = *(const float4*)(ar + kk * 32 + 4);
      bf16x8 f;
      f[0] = (bf16_t)x.x; f[1] = (bf16_t)x.y; f[2] = (bf16_t)x.z; f[3] = (bf16_t)x.w;
      f[4] = (bf16_t)y.x; f[5] = (bf16_t)y.y; f[6] = (bf16_t)y.z; f[7] = (bf16_t)y.w;
      a[kk] = f;
    }
  } else {
#pragma unroll
    for (int kk = 0; kk < 24; kk++) {
      bf16x8 f;
#pragma unroll
      for (int e = 0; e < 8; e++) f[e] = (bf16_t)0.f;
      a[kk] = f;
    }
  }

  auto stage = [&](int buf, int nt) {
    const ulonglong2* src = (const ulonglong2*)(TSb + (size_t)nt * 16 * D);
#pragma unroll
    for (int j = 0; j < 6; j++) {
      int c = tid + j * 256;
      int rr = c / 96, w = c % 96;
      *(ulonglong2*)&lds[buf][rr * LDSROW + w * 8] = src[c];
    }
  };

  stage(0, 0);
  for (int nt = 0; nt < NTB; nt++) {
    __syncthreads();
    if (nt + 1 < NTB) stage((nt + 1) & 1, nt + 1);
    f32x4 acc = {0.f, 0.f, 0.f, 0.f};
    const bf16_t* brow = &lds[nt & 1][(lane & 15) * LDSROW + ((lane >> 4) * 8)];
#pragma unroll
    for (int kk = 0; kk < 24; kk++) {
      bf16x8 b = *(const bf16x8*)(brow + kk * 32);
      acc = __builtin_amdgcn_mfma_f32_16x16x32_bf16(a[kk], b, acc, 0, 0, 0);
    }
    const int bcol = nt * 16 + (lane & 15);
    const int q0   = rowbase + ((lane >> 4) << 2);
    float* dst = sim + (size_t)bcol * ld + q0;
    if (q0 + 3 < Q) {
      *(f32x4*)dst = acc;
    } else {
#pragma unroll
      for (int j = 0; j < 4; j++)
        if (q0 + j < Q) dst[j] = acc[j];
    }
  }
}

// ---------------- K4: per-row top-16 + exact f64 rescore -> top-8 ----------
__device__ inline unsigned long long pack_key(float v, int q) {
  unsigned u = __float_as_uint(v);
  u = (u & 0x80000000u) ? ~u : (u | 0x80000000u);  // order-preserving map
  return ((unsigned long long)u << 32) | (unsigned)(0xFFFFFFFFu - (unsigned)q);
}

__global__ __launch_bounds__(256) void topk_rescore(const float* __restrict__ sim,
                                                    const float* __restrict__ SUPn,
                                                    const float* __restrict__ TSn,
                                                    int* __restrict__ topk,
                                                    int Q, int ld) {
  __shared__ unsigned long long sk[256][16];
  __shared__ float tsrow[D];
  __shared__ double sval[16];
  __shared__ int    sidx[16];
  const int b = blockIdx.x, tid = threadIdx.x;
#pragma unroll
  for (int j = 0; j < 3; j++) tsrow[tid + 256 * j] = TSn[(size_t)b * D + tid + 256 * j];

  const float* row = sim + (size_t)b * ld;
  unsigned long long best[16];
#pragma unroll
  for (int k = 0; k < 16; k++) best[k] = 0ull;
  for (int q = tid; q < Q; q += 256) {
    unsigned long long key = pack_key(row[q], q);
    if (key > best[15]) {
      best[15] = key;
      for (int k = 15; k > 0; k--) {
        if (best[k] > best[k - 1]) {
          unsigned long long t = best[k]; best[k] = best[k - 1]; best[k - 1] = t;
        } else break;
      }
    }
  }
#pragma unroll
  for (int k = 0; k < 16; k++) sk[tid][k] = best[k];
  for (int stride = 128; stride >= 1; stride >>= 1) {
    __syncthreads();
    if (tid < stride) {
      unsigned long long out[16];
      int pa = 0, pb = 0;
#pragma unroll
      for (int k = 0; k < 16; k++) {
        unsigned long long va = sk[tid][pa], vb = sk[tid + stride][pb];
        if (va >= vb) { out[k] = va; pa++; }
        else          { out[k] = vb; pb++; }
      }
#pragma unroll
      for (int k = 0; k < 16; k++) sk[tid][k] = out[k];
    }
  }
  __syncthreads();

  // exact f64 rescore of the 16 candidates (1 wave each, 4 waves x 4 rounds)
  const int lane = tid & 63, w = tid >> 6;
  for (int c = w; c < 16; c += 4) {
    int q = (int)(0xFFFFFFFFu - (unsigned)(sk[0][c] & 0xFFFFFFFFull));
    const float* sr = SUPn + (size_t)q * D;
    double dot = 0.0;
#pragma unroll
    for (int i = 0; i < 12; i++)
      dot += (double)sr[lane + 64 * i] * (double)tsrow[lane + 64 * i];
#pragma unroll
    for (int m = 32; m; m >>= 1) dot += __shfl_xor(dot, m);
    if (lane == 0) { sval[c] = dot; sidx[c] = q; }
  }
  __syncthreads();
  if (tid == 0) {
    for (int i = 1; i < 16; i++) {
      double v = sval[i]; int ix = sidx[i];
      int j = i - 1;
      while (j >= 0 && (sval[j] < v || (sval[j] == v && sidx[j] > ix))) {
        sval[j + 1] = sval[j]; sidx[j + 1] = sidx[j]; j--;
      }
      sval[j + 1] = v; sidx[j + 1] = ix;
    }
#pragma unroll
    for (int k = 0; k < 8; k++) topk[b * 8 + k] = sidx[k];
  }
}

// ---------------- K5: gather + positive + pos_sim + NNCL row loss ----------
__global__ __launch_bounds__(256) void gather_nncl(const float* __restrict__ SUPn,
                                                   const float* __restrict__ TSn,
                                                   const int* __restrict__ topk,
                                                   float* __restrict__ out,
                                                   double* __restrict__ row_loss) {
  __shared__ int idx[8];
  __shared__ double red[4];
  __shared__ float tsb[D];
  const int b = blockIdx.x, tid = threadIdx.x;
  if (tid < 8) idx[tid] = topk[b * 8 + tid];
  float tsv[3];
#pragma unroll
  for (int j = 0; j < 3; j++) {
    tsv[j] = TSn[(size_t)b * D + tid + 256 * j];
    tsb[tid + 256 * j] = tsv[j];
  }
  __syncthreads();
  float mean[3] = {0.f, 0.f, 0.f};
#pragma unroll
  for (int k = 0; k < 8; k++) {
    const float* sr = SUPn + (size_t)idx[k] * D;
    float* orow = out + ((size_t)b * 8 + k) * D;
#pragma unroll
    for (int j = 0; j < 3; j++) {
      float x = sr[tid + 256 * j];
      orow[tid + 256 * j] = x;
      mean[j] += x;
    }
  }
#pragma unroll
  for (int j = 0; j < 3; j++) mean[j] *= 0.125f;
  double ss = 0.0;
#pragma unroll
  for (int j = 0; j < 3; j++) ss += (double)mean[j] * mean[j];
  ss = blk_sum(ss, red);
  double inv = 1.0 / fmax(sqrt(ss), 1e-12);
  double dot = 0.0;
#pragma unroll
  for (int j = 0; j < 3; j++)
    dot += (double)tsv[j] * ((double)mean[j] * inv);
  dot = blk_sum(dot, red);
  const double p = dot / (double)0.07f;

  // ---- NNCL logsumexp over columns c = tid ----
  const float* tc = TSn + (size_t)tid * D;
  double dot2 = 0.0;
  for (int e = 0; e < D; e += 4) {
    float4 t4 = *(const float4*)(tc + e);
    dot2 += (double)tsb[e] * t4.x + (double)tsb[e + 1] * t4.y +
            (double)tsb[e + 2] * t4.z + (double)tsb[e + 3] * t4.w;
  }
  const bool diag = (tid == b);
  double logit = dot2 / (double)0.07f;
  double m = blk_max(diag ? -1e300 : logit, red);
  m = fmax(m, p);
  double term = diag ? 0.0 : exp(logit - m);
  double ssum = blk_sum(term, red);
  ssum += exp(p - m);
  if (tid == 0) row_loss[b] = (log(ssum) + m) - p;
}

// ---------------- K6: finalize scalars --------------------------------------
__global__ __launch_bounds__(256) void finalize(const float* __restrict__ maxpart,
                                                const double* __restrict__ row_loss,
                                                float* __restrict__ d_out, int out_size,
                                                int V, int B, int vstride) {
  __shared__ double red[4];
  const int tid = threadIdx.x;
  double s1 = 0.0;
  for (int v = tid; v < V; v += 256) {
    float mx = fmaxf(maxpart[v], maxpart[vstride + v]);
    s1 += 2.0 - 2.0 * (double)mx;
  }
  s1 = blk_sum(s1, red);
  __syncthreads();
  double s2 = 0.0;
  for (int b = tid; b < B; b += 256) s2 += row_loss[b];
  s2 = blk_sum(s2, red);
  if (tid == 0) {
    d_out[out_size - 2] = (float)(s1 / ((double)V * (double)D));
    d_out[out_size - 1] = (float)(s2 / (double)B);
  }
}

// ---------------- host launcher ---------------------------------------------
extern "C" void kernel_launch(void* const* d_in, const int* in_sizes, int n_in,
                              void* d_out, int out_size, void* d_ws, size_t ws_size,
                              hipStream_t stream) {
  const float* TS  = (const float*)d_in[0];
  const float* W   = (const float*)d_in[1];
  const float* T   = (const float*)d_in[2];
  const float* SUP = (const float*)d_in[3];
  const int B = in_sizes[0] / D;   // 256
  const int V = in_sizes[1] / D;   // 50257
  const int U = in_sizes[2] / D;   // 1000
  const int Q = in_sizes[3] / D;   // 10000
  const int NT   = (U + 15) / 16;  // 63
  const int UPAD = NT * 16;        // 1008
  const int VPAD = (V + 63) & ~63; // 50304
  const int QPAD = (Q + 63) & ~63; // 10048
  const int NTB  = B / 16;         // 16

  char* ws = (char*)d_ws;
  size_t off = 0;
  auto alloc = [&](size_t bytes) -> char* {
    char* p = ws + off;
    off = (off + bytes + 255) & ~(size_t)255;
    return p;
  };
  unsigned int* t8 = (unsigned int*)alloc((size_t)UPAD * D);  // fp8 bytes
  float*  maxpart = (float*) alloc((size_t)2 * VPAD * 4);
  float*  ts_n   = (float*) alloc((size_t)B * D * 4);
  bf16_t* ts_bf  = (bf16_t*)alloc((size_t)B * D * 2);
  float*  sup_n  = (float*) alloc((size_t)Q * D * 4);
  float*  simf   = (float*) alloc((size_t)B * QPAD * 4);
  int*    tki    = (int*)   alloc((size_t)B * 8 * 4);
  double* rloss  = (double*)alloc((size_t)B * 8);
  (void)ws_size; (void)n_in;

  norm_rows<<<UPAD / 4, 256, 0, stream>>>(T, nullptr, nullptr, t8, 16.f, U, UPAD);
  norm_rows<<<B / 4, 256, 0, stream>>>(TS, ts_n, ts_bf, nullptr, 0.f, B, B);
  norm_rows<<<(Q + 3) / 4, 256, 0, stream>>>(SUP, sup_n, nullptr, nullptr, 0.f, Q, Q);

  dim3 gms(VPAD / 64, 2);  // y = U-half (2-way split for occupancy)
  maxsim_gemm<<<gms, 256, 0, stream>>>(W, (const unsigned char*)t8,
                                       maxpart, V, U, NT, VPAD);

  simf_gemm<<<QPAD / 64, 256, 0, stream>>>(sup_n, ts_bf, simf, Q, QPAD, NTB);
  topk_rescore<<<B, 256, 0, stream>>>(simf, sup_n, ts_n, tki, Q, QPAD);
  gather_nncl<<<B, 256, 0, stream>>>(sup_n, ts_n, tki, (float*)d_out, rloss);
  finalize<<<1, 256, 0, stream>>>(maxpart, rloss, (float*)d_out, out_size, V, B, VPAD);
}